// Round 1
// baseline (586.557 us; speedup 1.0000x reference)
//
#include <hip/hip_runtime.h>

// PhonologicalLoopMemory: out[b] = concat(recent[0..3], rehearsal), each slice 128*256 fp32.
//   recent[0] = features[b]                     (buf[pos] was overwritten with features)
//   recent[j] = 0.9 * feature_buffer[b, (pos-j) & 63]   for j=1..3, if j < num_valid else 0
//   rehearsal = features[b]
//   num_valid = buffer_filled[b] ? 64 : pos+1
// Pure memory movement; no buffer write-back needed (buf is not an output).

constexpr int FEATURE_DIM = 128;
constexpr int WINDOW_LEN  = 256;
constexpr int BUFFER_LEN  = 64;
constexpr int NUM_RECENT  = 4;
constexpr int BATCH       = 64;
constexpr int FW   = FEATURE_DIM * WINDOW_LEN;   // 32768 floats per slice
constexpr int FW4  = FW / 4;                     // 8192 float4 per slice
constexpr int OUT4_PER_B = (NUM_RECENT + 1) * FW4;   // 40960 float4 per batch
constexpr int TOTAL4     = BATCH * OUT4_PER_B;       // 2,621,440 float4 total

__global__ __launch_bounds__(256) void plm_kernel(
    const float4* __restrict__ features,       // [B, FW4]
    const float4* __restrict__ feature_buffer, // [B, 64, FW4]
    const int*    __restrict__ current_pos,    // [B]
    const int*    __restrict__ buffer_filled,  // [B] (bool as int32)
    float4*       __restrict__ out)            // [B, 5, FW4]
{
    int i = blockIdx.x * blockDim.x + threadIdx.x;
    if (i >= TOTAL4) return;

    int b   = i / OUT4_PER_B;           // const-divisor, compiler emits mul_hi
    int rem = i - b * OUT4_PER_B;
    int j   = rem / FW4;                // slice index 0..4
    int k   = rem - j * FW4;            // float4 index within slice, coalesced

    float4 v;
    if (j == 0 || j == NUM_RECENT) {
        // recent[0] and rehearsal are both exactly features[b] (undecayed)
        v = features[b * FW4 + k];
    } else {
        int pos       = current_pos[b];
        int filled    = buffer_filled[b];
        int num_valid = filled ? BUFFER_LEN : (pos + 1);
        if (j < num_valid) {
            int p = (pos - j) & (BUFFER_LEN - 1);   // mod 64
            float4 s = feature_buffer[(b * BUFFER_LEN + p) * FW4 + k];
            v = make_float4(0.9f * s.x, 0.9f * s.y, 0.9f * s.z, 0.9f * s.w);
        } else {
            v = make_float4(0.0f, 0.0f, 0.0f, 0.0f);
        }
    }
    out[i] = v;
}

extern "C" void kernel_launch(void* const* d_in, const int* in_sizes, int n_in,
                              void* d_out, int out_size, void* d_ws, size_t ws_size,
                              hipStream_t stream) {
    const float4* features       = (const float4*)d_in[0];
    const float4* feature_buffer = (const float4*)d_in[1];
    const int*    current_pos    = (const int*)d_in[2];
    const int*    buffer_filled  = (const int*)d_in[3];
    float4*       out            = (float4*)d_out;

    int blocks = (TOTAL4 + 255) / 256;   // 10240 blocks
    plm_kernel<<<blocks, 256, 0, stream>>>(features, feature_buffer,
                                           current_pos, buffer_filled, out);
}

// Round 2
// 585.713 us; speedup vs baseline: 1.0014x; 1.0014x over previous
//
#include <hip/hip_runtime.h>

// PhonologicalLoopMemory: out[b] = concat(recent[0..3], rehearsal), each slice 128*256 fp32.
//   recent[0] = features[b]                     (buf[pos] overwritten with features before read)
//   recent[j] = 0.9 * feature_buffer[b, (pos-j) & 63]   for j=1..3, if j < num_valid else 0
//   rehearsal = features[b]
//   num_valid = buffer_filled[b] ? 64 : pos+1
// Pure memory movement. One thread per (b, k): features loaded once, written to
// slices 0 and 4; b is block-uniform (8192 float4/batch, 256 thr/block) so
// pos/filled/num_valid are wave-uniform -> no divergence, scalar branches.

constexpr int FEATURE_DIM = 128;
constexpr int WINDOW_LEN  = 256;
constexpr int BUFFER_LEN  = 64;
constexpr int NUM_RECENT  = 4;
constexpr int BATCH       = 64;
constexpr int FW   = FEATURE_DIM * WINDOW_LEN;   // 32768 floats per slice
constexpr int FW4  = FW / 4;                     // 8192 float4 per slice
constexpr int THREADS_TOTAL = BATCH * FW4;       // 524288

__global__ __launch_bounds__(256) void plm_kernel(
    const float4* __restrict__ features,       // [B, FW4]
    const float4* __restrict__ feature_buffer, // [B, 64, FW4]
    const int*    __restrict__ current_pos,    // [B]
    const int*    __restrict__ buffer_filled,  // [B] (bool as int32)
    float4*       __restrict__ out)            // [B, 5, FW4]
{
    int i = blockIdx.x * blockDim.x + threadIdx.x;   // 0 .. 524287
    int b = i >> 13;            // / FW4  (block-uniform)
    int k = i & (FW4 - 1);      // coalesced inner index

    int pos       = current_pos[b];
    int filled    = buffer_filled[b];
    int num_valid = filled ? BUFFER_LEN : (pos + 1);

    const float4 f = features[(size_t)b * FW4 + k];
    float4* ob = out + (size_t)b * (NUM_RECENT + 1) * FW4;

    ob[k]             = f;   // recent[0] (always valid: num_valid >= 1)
    ob[4 * FW4 + k]   = f;   // rehearsal

    const float4* bb = feature_buffer + (size_t)b * BUFFER_LEN * FW4;
#pragma unroll
    for (int j = 1; j < NUM_RECENT; ++j) {
        float4 v = make_float4(0.0f, 0.0f, 0.0f, 0.0f);
        if (j < num_valid) {                          // wave-uniform branch
            int p = (pos - j) & (BUFFER_LEN - 1);     // mod 64
            float4 s = bb[(size_t)p * FW4 + k];
            v = make_float4(0.9f * s.x, 0.9f * s.y, 0.9f * s.z, 0.9f * s.w);
        }
        ob[j * FW4 + k] = v;
    }
}

extern "C" void kernel_launch(void* const* d_in, const int* in_sizes, int n_in,
                              void* d_out, int out_size, void* d_ws, size_t ws_size,
                              hipStream_t stream) {
    const float4* features       = (const float4*)d_in[0];
    const float4* feature_buffer = (const float4*)d_in[1];
    const int*    current_pos    = (const int*)d_in[2];
    const int*    buffer_filled  = (const int*)d_in[3];
    float4*       out            = (float4*)d_out;

    int blocks = THREADS_TOTAL / 256;   // 2048 blocks
    plm_kernel<<<blocks, 256, 0, stream>>>(features, feature_buffer,
                                           current_pos, buffer_filled, out);
}